// Round 10
// baseline (167.595 us; speedup 1.0000x reference)
//
#include <hip/hip_runtime.h>
#include <hip/hip_bf16.h>

#define T_TOK 16384
#define DM 256
#define NE 8
#define HF 512
#define TM 32
#define XS_LD 264  // 256 + 8 shorts pad: row-to-row bank-granule walk, 2-way max (free)
#define HC_LD 520  // 512 + 8 shorts pad: same property (1040 B = 65 granules == 1 mod 32)

typedef __bf16 bf16x8 __attribute__((ext_vector_type(8)));
typedef float f32x4 __attribute__((ext_vector_type(4)));
typedef unsigned short u16x8 __attribute__((ext_vector_type(8)));

#define MFMA16(a, b, c) __builtin_amdgcn_mfma_f32_16x16x32_bf16((a), (b), (c), 0, 0, 0)

__device__ __forceinline__ unsigned short f2bf(float f) {
  unsigned u = __float_as_uint(f);
  u += 0x7fffu + ((u >> 16) & 1u);  // RNE (NaN not expected in this data)
  return (unsigned short)(u >> 16);
}

// Fast erf-based exact-form GELU (A&S 7.1.26, |err|<1.5e-7 << bf16 quantization).
__device__ __forceinline__ float gelu_f(float v) {
  float s = fabsf(v) * 0.70710678118654752f;
  float t = __builtin_amdgcn_rcpf(1.0f + 0.3275911f * s);
  float p = t * (0.254829592f +
            t * (-0.284496736f +
            t * (1.421413741f +
            t * (-1.453152027f + t * 1.061405429f))));
  float e = 1.0f - p * __expf(-s * s);
  e = copysignf(e, v);
  return 0.5f * v * (1.0f + e);
}

// ---- pack: fp32 [E][K][N] -> lane-major MFMA B-fragment tiles (16n x 32k) --------
// elem index: e*K*N + ((n>>4)*(K/32) + (k>>5))*512 + ((k>>3)&3)*128 + (n&15)*8 + (k&7)
__device__ __forceinline__ void pack_body(const float* __restrict__ in,
                                          unsigned short* __restrict__ out,
                                          int K, int N, int idx) {
  int n = idx & (N - 1);
  int rest = idx / N;
  int kq = rest & ((K >> 3) - 1);
  int eidx = rest / (K >> 3);
  int k0 = kq * 8;
  const float* src = in + ((size_t)eidx * K + k0) * N + n;
  u16x8 pk;
#pragma unroll
  for (int j = 0; j < 8; j++) pk[j] = f2bf(src[(size_t)j * N]);
  size_t baseo = (size_t)eidx * K * N +
                 (size_t)((n >> 4) * (K >> 5) + (k0 >> 5)) * 512 +
                 (size_t)(((k0 >> 3) & 3) * 128 + (n & 15) * 8);
  *reinterpret_cast<u16x8*>(out + baseo) = pk;
}

// ---- prep: pack W1/W2 (blocks 0..1023) + gate & x->bf16 (blocks 1024..1279) ------
__global__ __launch_bounds__(256) void prep_kernel(
    const float* __restrict__ W1, const float* __restrict__ W2,
    unsigned short* __restrict__ w1p, unsigned short* __restrict__ w2p,
    const float* __restrict__ x, unsigned short* __restrict__ x16,
    const float* __restrict__ Wg, const float* __restrict__ bg,
    int* __restrict__ cnts, int* __restrict__ list) {
  __shared__ float wg_s[DM * NE];  // 8 KB (gate path only)
  __shared__ int hist[NE], base_s[NE], rank[NE];
  int b = blockIdx.x;
  int tid = threadIdx.x;
  if (b < 512) {
    pack_body(W1, w1p, DM, HF, b * 256 + tid);
    return;
  }
  if (b < 1024) {
    pack_body(W2, w2p, HF, DM, (b - 512) * 256 + tid);
    return;
  }
  // ---- gate: 4 threads/token fp64 split-D + shfl reduce; also writes x16 ----
  int gb = b - 1024;
  {  // vectorized Wg stage: 2x float4 per thread
    float4 wv0 = *reinterpret_cast<const float4*>(Wg + tid * 8);
    float4 wv1 = *reinterpret_cast<const float4*>(Wg + tid * 8 + 4);
    *reinterpret_cast<float4*>(&wg_s[tid * 8]) = wv0;
    *reinterpret_cast<float4*>(&wg_s[tid * 8 + 4]) = wv1;
  }
  if (tid < NE) { hist[tid] = 0; rank[tid] = 0; }
  __syncthreads();

  int tl = tid >> 2;   // token within block (4-lane groups never straddle a wave)
  int cg = tid & 3;    // d-chunk 0..3, 64 floats each
  int t = gb * 64 + tl;
  const float* xr = x + (size_t)t * DM + cg * 64;
  unsigned short* x16r = x16 + (size_t)t * DM + cg * 64;
  double acc[NE];
#pragma unroll
  for (int i = 0; i < NE; i++) acc[i] = 0.0;
  for (int d = 0; d < 64; d += 4) {
    float4 xv = *reinterpret_cast<const float4*>(xr + d);
    {  // fold: bf16 cast of x (row already in registers -> zero extra reads)
      unsigned long long pk = (unsigned long long)f2bf(xv.x) |
                              ((unsigned long long)f2bf(xv.y) << 16) |
                              ((unsigned long long)f2bf(xv.z) << 32) |
                              ((unsigned long long)f2bf(xv.w) << 48);
      *reinterpret_cast<unsigned long long*>(x16r + d) = pk;
    }
    const float* w0 = &wg_s[(cg * 64 + d) * NE];
    float xa[4] = {xv.x, xv.y, xv.z, xv.w};
#pragma unroll
    for (int dd = 0; dd < 4; dd++) {  // 2x ds_read_b128 per d-row
      float4 wa = *reinterpret_cast<const float4*>(w0 + dd * NE);
      float4 wb = *reinterpret_cast<const float4*>(w0 + dd * NE + 4);
      double xd = (double)xa[dd];
      acc[0] += xd * (double)wa.x; acc[1] += xd * (double)wa.y;
      acc[2] += xd * (double)wa.z; acc[3] += xd * (double)wa.w;
      acc[4] += xd * (double)wb.x; acc[5] += xd * (double)wb.y;
      acc[6] += xd * (double)wb.z; acc[7] += xd * (double)wb.w;
    }
  }
#pragma unroll
  for (int i = 0; i < NE; i++) {
    acc[i] += __shfl_xor(acc[i], 1, 64);
    acc[i] += __shfl_xor(acc[i], 2, 64);
    acc[i] += (double)bg[i];
  }
  int e1 = 0;
#pragma unroll
  for (int i = 1; i < NE; i++) if (acc[i] > acc[e1]) e1 = i;  // ties -> lower index
  int e2 = -1;
#pragma unroll
  for (int i = 0; i < NE; i++) {
    if (i == e1) continue;
    if (e2 < 0 || acc[i] > acc[e2]) e2 = i;
  }
  if (cg == 0) {
    atomicAdd(&hist[e1], 1);
    atomicAdd(&hist[e2], 1);
  }
  __syncthreads();
  if (tid < NE) base_s[tid] = atomicAdd(&cnts[tid], hist[tid]);
  __syncthreads();
  if (cg == 0) {
    int r1 = atomicAdd(&rank[e1], 1);
    list[e1 * T_TOK + base_s[e1] + r1] = t;
    int r2 = atomicAdd(&rank[e2], 1);
    list[e2 * T_TOK + base_s[e2] + r2] = t;
  }
}

// ---------------- grouped FFN: 32-token tile, 8 waves, occupancy-first ------------
// Full Hc in LDS (no Xs overlay) -> exactly 2 barriers. Per-wave tiling shrunk so
// accumulators fit 6 waves/SIMD: GEMM1 nt=4 (pacc 32 regs), GEMM2 nt=2 (oacc 16,
// pacc dead). launch_bounds(512,6) -> 3 blocks x 8 waves = 24 waves/CU (~3x r9's
// residency); plain in-loop B loads (r8 showed hand rotation hurts; TLP hides).
__global__ __launch_bounds__(512, 6) void ffn_kernel(
    const unsigned short* __restrict__ x16, const unsigned short* __restrict__ w1p,
    const float* __restrict__ b1, const unsigned short* __restrict__ w2p,
    const float* __restrict__ b2, const int* __restrict__ cnts,
    const int* __restrict__ list, float* __restrict__ out) {
  __shared__ unsigned short Xs[TM * XS_LD];  // 16.9 KB
  __shared__ unsigned short Hc[TM * HC_LD];  // 33.3 KB
  __shared__ int tok[TM];

  int e = blockIdx.x & 7;     // expert <-> XCD binding
  int tile = blockIdx.x >> 3;
  int cnt = cnts[e];
  int base = tile * TM;
  if (base >= cnt) return;
  int rowsv = min(TM, cnt - base);

  int tid = threadIdx.x;
  int w = tid >> 6, lane = tid & 63;   // 8 waves
  int quad = lane >> 4, l16 = lane & 15;

  const unsigned short* w1e = w1p + (size_t)e * (HF * DM) + lane * 8;
  const unsigned short* w2e = w2p + (size_t)e * (DM * HF) + lane * 8;

  {  // stage X tile: bf16 copy, gathered rows, 16 threads/row (2 x 16B each)
    int r = tid >> 4, cg = tid & 15;
    int token = -1;
    if (r < rowsv) token = list[e * T_TOK + base + r];
    if (cg == 0) tok[r] = token;
    unsigned short* xrow = &Xs[r * XS_LD + cg * 16];
    if (token >= 0) {
      const u16x8* src = reinterpret_cast<const u16x8*>(x16 + (size_t)token * DM + cg * 16);
      *reinterpret_cast<u16x8*>(xrow) = src[0];
      *reinterpret_cast<u16x8*>(xrow + 8) = src[1];
    } else {
      u16x8 z = {0, 0, 0, 0, 0, 0, 0, 0};
      *reinterpret_cast<u16x8*>(xrow) = z;
      *reinterpret_cast<u16x8*>(xrow + 8) = z;
    }
  }
  __syncthreads();

  f32x4 zero4 = {0.f, 0.f, 0.f, 0.f};

  // ===== GEMM1: wave w -> h-cols [w*64, +64), K = 256 =====
  {
    f32x4 pacc[2][4];
#pragma unroll
    for (int mt = 0; mt < 2; mt++)
#pragma unroll
      for (int nt = 0; nt < 4; nt++) pacc[mt][nt] = zero4;
#pragma unroll
    for (int ks = 0; ks < 8; ks++) {
      bf16x8 bfr[4];
#pragma unroll
      for (int nt = 0; nt < 4; nt++)
        bfr[nt] = *reinterpret_cast<const bf16x8*>(w1e + (size_t)((w * 4 + nt) * 8 + ks) * 512);
      bf16x8 a[2];
#pragma unroll
      for (int mt = 0; mt < 2; mt++)
        a[mt] = *reinterpret_cast<const bf16x8*>(&Xs[(mt * 16 + l16) * XS_LD + ks * 32 + quad * 8]);
#pragma unroll
      for (int nt = 0; nt < 4; nt++)
#pragma unroll
        for (int mt = 0; mt < 2; mt++)
          pacc[mt][nt] = MFMA16(a[mt], bfr[nt], pacc[mt][nt]);
    }
    // gelu -> Hc (own region; Xs stays intact, no extra barrier)
#pragma unroll
    for (int nt = 0; nt < 4; nt++) {
      float bias1 = b1[e * HF + w * 64 + nt * 16 + l16];
#pragma unroll
      for (int mt = 0; mt < 2; mt++)
#pragma unroll
        for (int r = 0; r < 4; r++) {
          int row = mt * 16 + quad * 4 + r;
          Hc[row * HC_LD + w * 64 + nt * 16 + l16] = f2bf(gelu_f(pacc[mt][nt][r] + bias1));
        }
    }
  }
  __syncthreads();  // Hc fully ready

  // ===== GEMM2: wave w -> d-cols [w*32, +32), K = 512 =====
  f32x4 oacc[2][2];
#pragma unroll
  for (int mt = 0; mt < 2; mt++)
#pragma unroll
    for (int nt = 0; nt < 2; nt++) oacc[mt][nt] = zero4;
#pragma unroll
  for (int ks2 = 0; ks2 < 16; ks2++) {
    bf16x8 bfr[2];
#pragma unroll
    for (int nt = 0; nt < 2; nt++)
      bfr[nt] = *reinterpret_cast<const bf16x8*>(w2e + (size_t)((w * 2 + nt) * 16 + ks2) * 512);
    bf16x8 a[2];
#pragma unroll
    for (int mt = 0; mt < 2; mt++)
      a[mt] = *reinterpret_cast<const bf16x8*>(&Hc[(mt * 16 + l16) * HC_LD + ks2 * 32 + quad * 8]);
#pragma unroll
    for (int nt = 0; nt < 2; nt++)
#pragma unroll
      for (int mt = 0; mt < 2; mt++)
        oacc[mt][nt] = MFMA16(a[mt], bfr[nt], oacc[mt][nt]);
  }

  // ===== epilogue: scatter-add (+b2 per expert hit) =====
  float b2v[2];
#pragma unroll
  for (int nt = 0; nt < 2; nt++) b2v[nt] = b2[e * DM + w * 32 + nt * 16 + l16];
#pragma unroll
  for (int mt = 0; mt < 2; mt++) {
#pragma unroll
    for (int r = 0; r < 4; r++) {
      int m = mt * 16 + quad * 4 + r;
      int token = tok[m];
      if (token < 0) continue;
      float* orow = out + (size_t)token * DM;
#pragma unroll
      for (int nt = 0; nt < 2; nt++) {
        int d = w * 32 + nt * 16 + l16;
        atomicAdd(&orow[d], oacc[mt][nt][r] + b2v[nt]);
      }
    }
  }
}

extern "C" void kernel_launch(void* const* d_in, const int* in_sizes, int n_in,
                              void* d_out, int out_size, void* d_ws, size_t ws_size,
                              hipStream_t stream) {
  (void)in_sizes; (void)n_in; (void)ws_size;
  const float* x  = (const float*)d_in[0];
  const float* Wg = (const float*)d_in[1];
  const float* bg = (const float*)d_in[2];
  const float* W1 = (const float*)d_in[3];
  const float* b1 = (const float*)d_in[4];
  const float* W2 = (const float*)d_in[5];
  const float* b2 = (const float*)d_in[6];
  float* out = (float*)d_out;

  char* ws = (char*)d_ws;
  int* cnts = (int*)ws;                                                   // 256 B
  int* list = (int*)(ws + 256);                                           // 512 KB
  unsigned short* w1p = (unsigned short*)(ws + 256 + 524288);             // 2 MB
  unsigned short* w2p = (unsigned short*)(ws + 256 + 524288 + 2097152);   // 2 MB
  unsigned short* x16 = (unsigned short*)(ws + 256 + 524288 + 2097152 + 2097152);  // 8.4 MB

  hipMemsetAsync(cnts, 0, 256, stream);
  hipMemsetAsync(d_out, 0, (size_t)out_size * sizeof(float), stream);  // HW memset node

  // prep: blocks [0,1024) pack W1/W2; [1024,1280) gate + x->bf16.
  // W1 is [E][D][H] = [e][k][n] (K=256,N=512); W2 is [E][H][D] (K=512,N=256).
  hipLaunchKernelGGL(prep_kernel, dim3(1280), dim3(256), 0, stream,
                     W1, W2, w1p, w2p, x, x16, Wg, bg, cnts, list);
  hipLaunchKernelGGL(ffn_kernel, dim3(NE * 512), dim3(512), 0, stream,
                     x16, w1p, b1, w2p, b2, cnts, list, out);
}

// Round 11
// 135.391 us; speedup vs baseline: 1.2379x; 1.2379x over previous
//
#include <hip/hip_runtime.h>
#include <hip/hip_bf16.h>

#define T_TOK 16384
#define DM 256
#define NE 8
#define HF 512
#define TM 32
#define XS_LD 264  // 256 + 8 shorts pad: row stride 528 B, ~2-way max on b128 reads

typedef __bf16 bf16x8 __attribute__((ext_vector_type(8)));
typedef float f32x4 __attribute__((ext_vector_type(4)));
typedef unsigned short u16x8 __attribute__((ext_vector_type(8)));

#define MFMA16(a, b, c) __builtin_amdgcn_mfma_f32_16x16x32_bf16((a), (b), (c), 0, 0, 0)

__device__ __forceinline__ unsigned short f2bf(float f) {
  unsigned u = __float_as_uint(f);
  u += 0x7fffu + ((u >> 16) & 1u);  // RNE (NaN not expected in this data)
  return (unsigned short)(u >> 16);
}

// Fast erf-based exact-form GELU (A&S 7.1.26, |err|<1.5e-7 << bf16 quantization).
__device__ __forceinline__ float gelu_f(float v) {
  float s = fabsf(v) * 0.70710678118654752f;
  float t = __builtin_amdgcn_rcpf(1.0f + 0.3275911f * s);
  float p = t * (0.254829592f +
            t * (-0.284496736f +
            t * (1.421413741f +
            t * (-1.453152027f + t * 1.061405429f))));
  float e = 1.0f - p * __expf(-s * s);
  e = copysignf(e, v);
  return 0.5f * v * (1.0f + e);
}

// ---- pack: fp32 [E][K][N] -> lane-major MFMA B-fragment tiles (16n x 32k) --------
// elem index: e*K*N + ((n>>4)*(K/32) + (k>>5))*512 + ((k>>3)&3)*128 + (n&15)*8 + (k&7)
__device__ __forceinline__ void pack_body(const float* __restrict__ in,
                                          unsigned short* __restrict__ out,
                                          int K, int N, int idx) {
  int n = idx & (N - 1);
  int rest = idx / N;
  int kq = rest & ((K >> 3) - 1);
  int eidx = rest / (K >> 3);
  int k0 = kq * 8;
  const float* src = in + ((size_t)eidx * K + k0) * N + n;
  u16x8 pk;
#pragma unroll
  for (int j = 0; j < 8; j++) pk[j] = f2bf(src[(size_t)j * N]);
  size_t baseo = (size_t)eidx * K * N +
                 (size_t)((n >> 4) * (K >> 5) + (k0 >> 5)) * 512 +
                 (size_t)(((k0 >> 3) & 3) * 128 + (n & 15) * 8);
  *reinterpret_cast<u16x8*>(out + baseo) = pk;
}

// ---- prep: pack W1 (512 blocks) + pack W2 (512 blocks) + gate (256 blocks) -------
// Gate list entries carry a SLOT bit: slot0 = token's top-1 hit, slot1 = top-2 hit.
// ffn writes slot0 -> out, slot1 -> part1 (both non-atomic); combine sums.
__global__ __launch_bounds__(256) void prep_kernel(
    const float* __restrict__ W1, const float* __restrict__ W2,
    unsigned short* __restrict__ w1p, unsigned short* __restrict__ w2p,
    const float* __restrict__ x, const float* __restrict__ Wg,
    const float* __restrict__ bg, int* __restrict__ cnts, int* __restrict__ list) {
  __shared__ float wg_s[DM * NE];  // 8 KB (gate path only)
  __shared__ int hist[NE], base_s[NE], rank[NE];
  int b = blockIdx.x;
  int tid = threadIdx.x;
  if (b < 512) {
    pack_body(W1, w1p, DM, HF, b * 256 + tid);
    return;
  }
  if (b < 1024) {
    pack_body(W2, w2p, HF, DM, (b - 512) * 256 + tid);
    return;
  }
  // ---- gate: 4 threads/token fp64 split-D + shfl reduce ----
  int gb = b - 1024;
  {  // vectorized Wg stage: 2x float4 per thread
    float4 wv0 = *reinterpret_cast<const float4*>(Wg + tid * 8);
    float4 wv1 = *reinterpret_cast<const float4*>(Wg + tid * 8 + 4);
    *reinterpret_cast<float4*>(&wg_s[tid * 8]) = wv0;
    *reinterpret_cast<float4*>(&wg_s[tid * 8 + 4]) = wv1;
  }
  if (tid < NE) { hist[tid] = 0; rank[tid] = 0; }
  __syncthreads();

  int tl = tid >> 2;   // token within block (4-lane groups never straddle a wave)
  int cg = tid & 3;    // d-chunk 0..3, 64 floats each
  int t = gb * 64 + tl;
  const float* xr = x + (size_t)t * DM + cg * 64;
  double acc[NE];
#pragma unroll
  for (int i = 0; i < NE; i++) acc[i] = 0.0;
  for (int d = 0; d < 64; d += 4) {
    float4 xv = *reinterpret_cast<const float4*>(xr + d);
    const float* w0 = &wg_s[(cg * 64 + d) * NE];
    float xa[4] = {xv.x, xv.y, xv.z, xv.w};
#pragma unroll
    for (int dd = 0; dd < 4; dd++) {  // 2x ds_read_b128 per d-row
      float4 wa = *reinterpret_cast<const float4*>(w0 + dd * NE);
      float4 wb = *reinterpret_cast<const float4*>(w0 + dd * NE + 4);
      double xd = (double)xa[dd];
      acc[0] += xd * (double)wa.x; acc[1] += xd * (double)wa.y;
      acc[2] += xd * (double)wa.z; acc[3] += xd * (double)wa.w;
      acc[4] += xd * (double)wb.x; acc[5] += xd * (double)wb.y;
      acc[6] += xd * (double)wb.z; acc[7] += xd * (double)wb.w;
    }
  }
#pragma unroll
  for (int i = 0; i < NE; i++) {
    acc[i] += __shfl_xor(acc[i], 1, 64);
    acc[i] += __shfl_xor(acc[i], 2, 64);
    acc[i] += (double)bg[i];
  }
  int e1 = 0;
#pragma unroll
  for (int i = 1; i < NE; i++) if (acc[i] > acc[e1]) e1 = i;  // ties -> lower index
  int e2 = -1;
#pragma unroll
  for (int i = 0; i < NE; i++) {
    if (i == e1) continue;
    if (e2 < 0 || acc[i] > acc[e2]) e2 = i;
  }
  if (cg == 0) {
    atomicAdd(&hist[e1], 1);
    atomicAdd(&hist[e2], 1);
  }
  __syncthreads();
  if (tid < NE) base_s[tid] = atomicAdd(&cnts[tid], hist[tid]);
  __syncthreads();
  if (cg == 0) {
    int r1 = atomicAdd(&rank[e1], 1);
    list[e1 * T_TOK + base_s[e1] + r1] = t;               // slot 0 (top-1 hit)
    int r2 = atomicAdd(&rank[e2], 1);
    list[e2 * T_TOK + base_s[e2] + r2] = t | (1 << 20);   // slot 1 (top-2 hit)
  }
}

// ---------------- grouped FFN: 32-token tile, 4 waves, 2x4 register tiling --------
// Round-7 verified structure, epilogue de-atomicized: slot0 contributions stream
// non-atomically into out, slot1 into part1 (each (slot,token,d) written exactly
// once). Removes 8.4M device-scope memory-side RMW atomics -- the round-0..10
// invariant WRITE_SIZE=2x-out signature identified them as write-through.
__global__ __launch_bounds__(256, 4) void ffn_kernel(
    const float* __restrict__ x, const unsigned short* __restrict__ w1p,
    const float* __restrict__ b1, const unsigned short* __restrict__ w2p,
    const float* __restrict__ b2, const int* __restrict__ cnts,
    const int* __restrict__ list, float* __restrict__ out,
    float* __restrict__ part1) {
  __shared__ unsigned short Xs[TM * XS_LD];  // 16.9KB: X tile, later Hc cols 256..511
  __shared__ unsigned short Hl[TM * XS_LD];  // 16.9KB: Hc cols 0..255
  __shared__ int tok[TM];

  int e = blockIdx.x & 7;     // expert <-> XCD binding
  int tile = blockIdx.x >> 3;
  int cnt = cnts[e];
  int base = tile * TM;
  if (base >= cnt) return;
  int rowsv = min(TM, cnt - base);

  int tid = threadIdx.x;
  int w = tid >> 6, lane = tid & 63;   // 4 waves
  int quad = lane >> 4, l16 = lane & 15;

  const unsigned short* w1e = w1p + (size_t)e * (HF * DM) + lane * 8;
  const unsigned short* w2e = w2p + (size_t)e * (DM * HF) + lane * 8;

  // early-issue first GEMM1 B-frags (independent of staging)
  bf16x8 bcur[4];
#pragma unroll
  for (int nt = 0; nt < 4; nt++)
    bcur[nt] = *reinterpret_cast<const bf16x8*>(w1e + (size_t)((w * 4 + nt) * 8) * 512);

  {  // stage X tile: fp32 -> bf16, gathered rows, 8 threads/row
    int r = tid >> 3, cg = tid & 7;
    int v = -1;
    if (r < rowsv) v = list[e * T_TOK + base + r];
    if (cg == 0) tok[r] = v;
    unsigned short* xrow = &Xs[r * XS_LD + cg * 32];
    if (v >= 0) {
      int token = v & 0xFFFFF;
      const float* xr = x + (size_t)token * DM + cg * 32;
#pragma unroll
      for (int j = 0; j < 8; j++) {
        float4 vv = *reinterpret_cast<const float4*>(xr + j * 4);
        unsigned long long pk = (unsigned long long)f2bf(vv.x) |
                                ((unsigned long long)f2bf(vv.y) << 16) |
                                ((unsigned long long)f2bf(vv.z) << 32) |
                                ((unsigned long long)f2bf(vv.w) << 48);
        *reinterpret_cast<unsigned long long*>(xrow + j * 4) = pk;
      }
    } else {
#pragma unroll
      for (int j = 0; j < 8; j++)
        *reinterpret_cast<unsigned long long*>(xrow + j * 4) = 0ull;
    }
  }
  __syncthreads();

  f32x4 zero4 = {0.f, 0.f, 0.f, 0.f};
  f32x4 pacc[2][4];

  // ===== GEMM1 chunk 0: h-cols w*64 .. +64 (4 n-tiles) =====
#pragma unroll
  for (int mt = 0; mt < 2; mt++)
#pragma unroll
    for (int nt = 0; nt < 4; nt++) pacc[mt][nt] = zero4;
#pragma unroll
  for (int ks = 0; ks < 8; ks++) {
    bf16x8 bn[4];
#pragma unroll
    for (int nt = 0; nt < 4; nt++) {
      int tn = (ks < 7) ? (w * 4 + nt) : (16 + w * 4 + nt);
      int kk = (ks < 7) ? (ks + 1) : 0;
      bn[nt] = *reinterpret_cast<const bf16x8*>(w1e + (size_t)(tn * 8 + kk) * 512);
    }
    bf16x8 a[2];
#pragma unroll
    for (int mt = 0; mt < 2; mt++)
      a[mt] = *reinterpret_cast<const bf16x8*>(&Xs[(mt * 16 + l16) * XS_LD + ks * 32 + quad * 8]);
#pragma unroll
    for (int nt = 0; nt < 4; nt++)
#pragma unroll
      for (int mt = 0; mt < 2; mt++)
        pacc[mt][nt] = MFMA16(a[mt], bcur[nt], pacc[mt][nt]);
#pragma unroll
    for (int nt = 0; nt < 4; nt++) bcur[nt] = bn[nt];
  }
  // gelu + write Hc-lo (separate region, no barrier needed before writes)
#pragma unroll
  for (int nt = 0; nt < 4; nt++) {
    float bias1 = b1[e * HF + w * 64 + nt * 16 + l16];
#pragma unroll
    for (int mt = 0; mt < 2; mt++)
#pragma unroll
      for (int r = 0; r < 4; r++) {
        int row = mt * 16 + quad * 4 + r;
        Hl[row * XS_LD + w * 64 + nt * 16 + l16] = f2bf(gelu_f(pacc[mt][nt][r] + bias1));
      }
  }

  // ===== GEMM1 chunk 1: h-cols 256 + w*64 .. +64 =====
#pragma unroll
  for (int mt = 0; mt < 2; mt++)
#pragma unroll
    for (int nt = 0; nt < 4; nt++) pacc[mt][nt] = zero4;
#pragma unroll
  for (int ks = 0; ks < 8; ks++) {
    bf16x8 bn[4];
#pragma unroll
    for (int nt = 0; nt < 4; nt++) {
      if (ks < 7) {
        bn[nt] = *reinterpret_cast<const bf16x8*>(
            w1e + (size_t)((16 + w * 4 + nt) * 8 + ks + 1) * 512);
      } else {  // prefetch first GEMM2 W2 k-tile before both barriers
        bn[nt] = *reinterpret_cast<const bf16x8*>(w2e + (size_t)((w * 4 + nt) * 16) * 512);
      }
    }
    bf16x8 a[2];
#pragma unroll
    for (int mt = 0; mt < 2; mt++)
      a[mt] = *reinterpret_cast<const bf16x8*>(&Xs[(mt * 16 + l16) * XS_LD + ks * 32 + quad * 8]);
#pragma unroll
    for (int nt = 0; nt < 4; nt++)
#pragma unroll
      for (int mt = 0; mt < 2; mt++)
        pacc[mt][nt] = MFMA16(a[mt], bcur[nt], pacc[mt][nt]);
#pragma unroll
    for (int nt = 0; nt < 4; nt++) bcur[nt] = bn[nt];
  }
  __syncthreads();  // all waves done reading Xs -> safe to overwrite with Hc-hi
#pragma unroll
  for (int nt = 0; nt < 4; nt++) {
    float bias1 = b1[e * HF + 256 + w * 64 + nt * 16 + l16];
#pragma unroll
    for (int mt = 0; mt < 2; mt++)
#pragma unroll
      for (int r = 0; r < 4; r++) {
        int row = mt * 16 + quad * 4 + r;
        Xs[row * XS_LD + w * 64 + nt * 16 + l16] = f2bf(gelu_f(pacc[mt][nt][r] + bias1));
      }
  }
  __syncthreads();  // Hc fully ready (lo in Hl, hi in Xs)

  // ===== GEMM2: d-cols w*64 .. +64, k = 0..511 =====
  f32x4 oacc[2][4];
#pragma unroll
  for (int mt = 0; mt < 2; mt++)
#pragma unroll
    for (int nt = 0; nt < 4; nt++) oacc[mt][nt] = zero4;
#pragma unroll
  for (int ks2 = 0; ks2 < 16; ks2++) {
    bf16x8 bn[4];
    if (ks2 < 15) {
#pragma unroll
      for (int nt = 0; nt < 4; nt++)
        bn[nt] = *reinterpret_cast<const bf16x8*>(
            w2e + (size_t)((w * 4 + nt) * 16 + ks2 + 1) * 512);
    }
    const unsigned short* hbase = (ks2 < 8) ? Hl : Xs;
    int col = (ks2 & 7) * 32 + quad * 8;
    bf16x8 a[2];
#pragma unroll
    for (int mt = 0; mt < 2; mt++)
      a[mt] = *reinterpret_cast<const bf16x8*>(&hbase[(mt * 16 + l16) * XS_LD + col]);
#pragma unroll
    for (int nt = 0; nt < 4; nt++)
#pragma unroll
      for (int mt = 0; mt < 2; mt++)
        oacc[mt][nt] = MFMA16(a[mt], bcur[nt], oacc[mt][nt]);
    if (ks2 < 15) {
#pragma unroll
      for (int nt = 0; nt < 4; nt++) bcur[nt] = bn[nt];
    }
  }

  // ===== epilogue: non-atomic slot-routed stores (+b2 per expert hit) =====
  float b2v[4];
#pragma unroll
  for (int nt = 0; nt < 4; nt++) b2v[nt] = b2[e * DM + w * 64 + nt * 16 + l16];
#pragma unroll
  for (int mt = 0; mt < 2; mt++) {
#pragma unroll
    for (int r = 0; r < 4; r++) {
      int m = mt * 16 + quad * 4 + r;
      int v = tok[m];
      if (v < 0) continue;
      int token = v & 0xFFFFF;
      float* orow = ((v >> 20) ? part1 : out) + (size_t)token * DM;
#pragma unroll
      for (int nt = 0; nt < 4; nt++) {
        int d = w * 64 + nt * 16 + l16;
        orow[d] = oacc[mt][nt][r] + b2v[nt];
      }
    }
  }
}

// ---- combine: out += part1 (every element of both written exactly once by ffn) ---
__global__ __launch_bounds__(256) void combine_kernel(
    float* __restrict__ out, const float* __restrict__ part1) {
  float4* o4 = reinterpret_cast<float4*>(out);
  const float4* p4 = reinterpret_cast<const float4*>(part1);
  int i0 = blockIdx.x * 256 + threadIdx.x;  // 1024 blocks: 4,194,304 floats total
#pragma unroll
  for (int j = 0; j < 4; j++) {
    int i = i0 + j * 262144;
    float4 a = o4[i], b = p4[i];
    a.x += b.x; a.y += b.y; a.z += b.z; a.w += b.w;
    o4[i] = a;
  }
}

extern "C" void kernel_launch(void* const* d_in, const int* in_sizes, int n_in,
                              void* d_out, int out_size, void* d_ws, size_t ws_size,
                              hipStream_t stream) {
  (void)in_sizes; (void)n_in; (void)ws_size; (void)out_size;
  const float* x  = (const float*)d_in[0];
  const float* Wg = (const float*)d_in[1];
  const float* bg = (const float*)d_in[2];
  const float* W1 = (const float*)d_in[3];
  const float* b1 = (const float*)d_in[4];
  const float* W2 = (const float*)d_in[5];
  const float* b2 = (const float*)d_in[6];
  float* out = (float*)d_out;

  char* ws = (char*)d_ws;
  int* cnts = (int*)ws;                                                   // 256 B
  int* list = (int*)(ws + 256);                                           // 512 KB
  unsigned short* w1p = (unsigned short*)(ws + 256 + 524288);             // 2 MB
  unsigned short* w2p = (unsigned short*)(ws + 256 + 524288 + 2097152);   // 2 MB
  float* part1 = (float*)(ws + 256 + 524288 + 2097152 + 2097152);         // 16.8 MB

  hipMemsetAsync(cnts, 0, 256, stream);
  // no out memset: every out element gets exactly one slot-0 store in ffn.

  // prep: blocks [0,512) pack W1, [512,1024) pack W2, [1024,1280) gate.
  // W1 is [E][D][H] = [e][k][n] (K=256,N=512); W2 is [E][H][D] (K=512,N=256).
  hipLaunchKernelGGL(prep_kernel, dim3(1280), dim3(256), 0, stream,
                     W1, W2, w1p, w2p, x, Wg, bg, cnts, list);
  hipLaunchKernelGGL(ffn_kernel, dim3(NE * 512), dim3(256), 0, stream,
                     x, w1p, b1, w2p, b2, cnts, list, out, part1);
  hipLaunchKernelGGL(combine_kernel, dim3(1024), dim3(256), 0, stream,
                     out, part1);
}